// Round 5
// baseline (558.404 us; speedup 1.0000x reference)
//
#include <hip/hip_runtime.h>

typedef __bf16 bf16x8 __attribute__((ext_vector_type(8)));
typedef __bf16 bf16x4 __attribute__((ext_vector_type(4)));
typedef float floatx4 __attribute__((ext_vector_type(4)));

#define AS1(p) ((const __attribute__((address_space(1))) unsigned int*)(p))
#define AS3(p) ((__attribute__((address_space(3))) unsigned int*)(p))

__device__ __forceinline__ void async_cp16(const void* g, void* l) {
  __builtin_amdgcn_global_load_lds(AS1(g), AS3(l), 16, 0, 0);
}

// ---------------------------------------------------------------------------
// Generic bf16 GEMM:  C[row][col] = scale * (sum_k A[row,k]*B[col,k] + bias)
// A: [M][K] k-contiguous (lda), B: [N][K] k-contiguous (ldb).
// grid = (N/128, M/128, batch).
// ---------------------------------------------------------------------------
template <bool OUT_F32>
__global__ __launch_bounds__(256, 2) void gemm_bt(
    const __bf16* __restrict__ A, const __bf16* __restrict__ B,
    void* __restrict__ Cv, const float* __restrict__ bias,
    const float* __restrict__ residual, int lda, int ldb, int ldc, long sA,
    long sB, long sC, long sR, int K, int bias_mode, float scale) {
  __shared__ alignas(16) __bf16 As[128 * 32];
  __shared__ alignas(16) __bf16 Bs[128 * 32];

  const int t = threadIdx.x;
  const int bz = blockIdx.z;
  const int m0 = blockIdx.y * 128;
  const int n0 = blockIdx.x * 128;

  const __bf16* Ab = A + (size_t)bz * sA;
  const __bf16* Bb = B + (size_t)bz * sB;

  const int sr = t >> 2;
  const int sc = t & 3;
  const __bf16* gA0 = Ab + (size_t)(m0 + sr) * lda + sc * 8;
  const __bf16* gA1 = gA0 + (size_t)64 * lda;
  const __bf16* gB0 = Bb + (size_t)(n0 + sr) * ldb + sc * 8;
  const __bf16* gB1 = gB0 + (size_t)64 * ldb;
  __bf16* lA0 = &As[t * 8];
  __bf16* lA1 = &As[(t + 256) * 8];
  __bf16* lB0 = &Bs[t * 8];
  __bf16* lB1 = &Bs[(t + 256) * 8];

  const int lane = t & 63;
  const int wv = t >> 6;
  const int wm = (wv & 1) * 64;
  const int wn = (wv >> 1) * 64;
  const int l15 = lane & 15;
  const int kg = lane >> 4;

  int aoff[4], boff[4];
#pragma unroll
  for (int i = 0; i < 4; ++i) aoff[i] = (wm + i * 16 + l15) * 32 + kg * 8;
#pragma unroll
  for (int j = 0; j < 4; ++j) boff[j] = (wn + j * 16 + l15) * 32 + kg * 8;

  floatx4 acc[4][4] = {};

  const int KT = K >> 5;
  for (int kt = 0; kt < KT; ++kt) {
    const size_t ko = (size_t)kt * 32;
    async_cp16(gA0 + ko, lA0);
    async_cp16(gA1 + ko, lA1);
    async_cp16(gB0 + ko, lB0);
    async_cp16(gB1 + ko, lB1);
    __syncthreads();
    bf16x8 af[4], bfr[4];
#pragma unroll
    for (int i = 0; i < 4; ++i) af[i] = *(const bf16x8*)&As[aoff[i]];
#pragma unroll
    for (int j = 0; j < 4; ++j) bfr[j] = *(const bf16x8*)&Bs[boff[j]];
#pragma unroll
    for (int i = 0; i < 4; ++i)
#pragma unroll
      for (int j = 0; j < 4; ++j)
        acc[i][j] = __builtin_amdgcn_mfma_f32_16x16x32_bf16(af[i], bfr[j],
                                                            acc[i][j], 0, 0, 0);
    __syncthreads();
  }

  const int r0 = m0 + wm + (kg << 2);
  const int c0 = n0 + wn + l15;
#pragma unroll
  for (int i = 0; i < 4; ++i) {
#pragma unroll
    for (int r = 0; r < 4; ++r) {
      const int row = r0 + i * 16 + r;
      float brow = 0.f;
      if (bias_mode == 1) brow = bias[row];
#pragma unroll
      for (int j = 0; j < 4; ++j) {
        const int col = c0 + j * 16;
        float v = acc[i][j][r];
        if (bias_mode == 1) v += brow;
        v *= scale;
        const size_t off = (size_t)row * ldc + col;
        if (OUT_F32) {
          float* Cf = (float*)Cv + (size_t)bz * sC;
          if (residual) v += residual[(size_t)bz * sR + off];
          Cf[off] = v;
        } else {
          __bf16* Cb = (__bf16*)Cv + (size_t)bz * sC;
          Cb[off] = (__bf16)v;
        }
      }
    }
  }
}

// ---------------------------------------------------------------------------
// QK^T GEMM: s[n][m] = sum_j G[n,j] Ht[m,j] + wvec[m]
// Writes P' = exp(s - Mb) (block-local max, coalesced via LDS transpose)
// and gstats[(row)*32 + mblk] = (Mb, Lb).  grid (32, 32, 4).
// ---------------------------------------------------------------------------
__global__ __launch_bounds__(256, 2) void gemm_qk(
    const __bf16* __restrict__ G, const __bf16* __restrict__ Ht,
    const float* __restrict__ wvec, __bf16* __restrict__ SP,
    float2* __restrict__ gstats) {
  __shared__ alignas(16) __bf16 As[128 * 32];
  __shared__ alignas(16) __bf16 Bs[128 * 32];
  __shared__ float smf[640];
  __shared__ alignas(16) __bf16 epi[128 * 136];

  const int t = threadIdx.x;
  const int bz = blockIdx.z;
  const int n0 = blockIdx.y * 128;  // query rows
  const int m0 = blockIdx.x * 128;  // key cols
  const long sH = 2097152;

  const __bf16* Ab = G + (size_t)bz * sH;
  const __bf16* Bb = Ht + (size_t)bz * sH;

  const int sr = t >> 2;
  const int sc = t & 3;
  const __bf16* gA0 = Ab + (size_t)(n0 + sr) * 512 + sc * 8;
  const __bf16* gA1 = gA0 + (size_t)64 * 512;
  const __bf16* gB0 = Bb + (size_t)(m0 + sr) * 512 + sc * 8;
  const __bf16* gB1 = gB0 + (size_t)64 * 512;
  __bf16* lA0 = &As[t * 8];
  __bf16* lA1 = &As[(t + 256) * 8];
  __bf16* lB0 = &Bs[t * 8];
  __bf16* lB1 = &Bs[(t + 256) * 8];

  const int lane = t & 63;
  const int wv = t >> 6;
  const int wm = (wv & 1) * 64;
  const int wn = (wv >> 1) * 64;
  const int l15 = lane & 15;
  const int kg = lane >> 4;

  int aoff[4], boff[4];
#pragma unroll
  for (int i = 0; i < 4; ++i) aoff[i] = (wm + i * 16 + l15) * 32 + kg * 8;
#pragma unroll
  for (int j = 0; j < 4; ++j) boff[j] = (wn + j * 16 + l15) * 32 + kg * 8;

  floatx4 acc[4][4] = {};

  for (int kt = 0; kt < 16; ++kt) {
    const size_t ko = (size_t)kt * 32;
    async_cp16(gA0 + ko, lA0);
    async_cp16(gA1 + ko, lA1);
    async_cp16(gB0 + ko, lB0);
    async_cp16(gB1 + ko, lB1);
    __syncthreads();
    bf16x8 af[4], bfr[4];
#pragma unroll
    for (int i = 0; i < 4; ++i) af[i] = *(const bf16x8*)&As[aoff[i]];
#pragma unroll
    for (int j = 0; j < 4; ++j) bfr[j] = *(const bf16x8*)&Bs[boff[j]];
#pragma unroll
    for (int i = 0; i < 4; ++i)
#pragma unroll
      for (int j = 0; j < 4; ++j)
        acc[i][j] = __builtin_amdgcn_mfma_f32_16x16x32_bf16(af[i], bfr[j],
                                                            acc[i][j], 0, 0, 0);
    __syncthreads();
  }

  // ---- epilogue: col bias, block-local softmax partials, P' via LDS ----
  const int wnh = wv >> 1;  // which 64-col half
#pragma unroll
  for (int j = 0; j < 4; ++j) {
    const float wb = wvec[(size_t)bz * 4096 + m0 + wn + j * 16 + l15];
#pragma unroll
    for (int i = 0; i < 4; ++i)
#pragma unroll
      for (int r = 0; r < 4; ++r) acc[i][j][r] += wb;
  }
  // per-row half max
#pragma unroll
  for (int i = 0; i < 4; ++i) {
#pragma unroll
    for (int r = 0; r < 4; ++r) {
      float mx = fmaxf(fmaxf(acc[i][0][r], acc[i][1][r]),
                       fmaxf(acc[i][2][r], acc[i][3][r]));
#pragma unroll
      for (int off = 1; off < 16; off <<= 1) mx = fmaxf(mx, __shfl_xor(mx, off));
      if (l15 == 0) smf[wnh * 128 + wm + i * 16 + (kg << 2) + r] = mx;
    }
  }
  __syncthreads();
  if (t < 128) smf[512 + t] = fmaxf(smf[t], smf[128 + t]);
  __syncthreads();
  // P' = exp(s - Mb) into epi; partial sums
#pragma unroll
  for (int i = 0; i < 4; ++i) {
#pragma unroll
    for (int r = 0; r < 4; ++r) {
      const int rl = wm + i * 16 + (kg << 2) + r;
      const float Mb = smf[512 + rl];
      float se = 0.f;
#pragma unroll
      for (int j = 0; j < 4; ++j) {
        const float p = __expf(acc[i][j][r] - Mb);
        se += p;
        epi[rl * 136 + wn + j * 16 + l15] = (__bf16)p;
      }
#pragma unroll
      for (int off = 1; off < 16; off <<= 1) se += __shfl_xor(se, off);
      if (l15 == 0) smf[wnh * 128 + rl] = se;
    }
  }
  __syncthreads();
  if (t < 128) {
    float2 o;
    o.x = smf[512 + t];
    o.y = smf[t] + smf[128 + t];
    gstats[((size_t)bz * 4096 + n0 + t) * 32 + blockIdx.x] = o;
  }
  // coalesced store of P'
  __bf16* Sb = SP + (size_t)bz * 16777216;
  const int rl2 = t >> 1, hf = t & 1;
  const __bf16* src = &epi[rl2 * 136 + hf * 64];
  __bf16* dst = Sb + (size_t)(n0 + rl2) * 4096 + m0 + hf * 64;
#pragma unroll
  for (int q = 0; q < 8; ++q) *(bf16x8*)(dst + q * 8) = *(const bf16x8*)(src + q * 8);
}

// ---------------------------------------------------------------------------
// Merge 32 partials per row -> alpha[row][kb] = exp(Mb - M)/L  (in gstats.x)
// ---------------------------------------------------------------------------
__global__ __launch_bounds__(256) void row_merge(float2* __restrict__ g) {
  const int row = blockIdx.x * 256 + threadIdx.x;
  float2* p = g + (size_t)row * 32;
  float M = -1e30f;
#pragma unroll
  for (int j = 0; j < 32; ++j) M = fmaxf(M, p[j].x);
  float L = 0.f;
#pragma unroll
  for (int j = 0; j < 32; ++j) L += p[j].y * __expf(p[j].x - M);
  const float inv = 1.0f / L;
#pragma unroll
  for (int j = 0; j < 32; ++j) p[j].x = __expf(p[j].x - M) * inv;
}

// ---------------------------------------------------------------------------
// PV GEMM: Z[n][c] = sum_m (P'[n,m]*alpha[n,m/128]) * Hc[c][m]
// m97 structure, 128x128 tile, A staged via VGPR with alpha multiply.
// grid (4, 32, 4) = 512 blocks.
// ---------------------------------------------------------------------------
__global__ __launch_bounds__(256, 2) void gemm_pv(
    const __bf16* __restrict__ SP, const __bf16* __restrict__ Hc,
    const float* __restrict__ alph, __bf16* __restrict__ Z) {
  __shared__ alignas(16) __bf16 Ps[128 * 32];
  __shared__ alignas(16) __bf16 Bs[128 * 32];

  const int t = threadIdx.x;
  const int bz = blockIdx.z;
  const int n0 = blockIdx.y * 128;
  const int c0 = blockIdx.x * 128;

  // A staging: row = t>>1 (0..127), 16-elem half = t&1
  const int arow = t >> 1;
  const int ahalf = t & 1;
  const __bf16* Sp = SP + ((size_t)bz * 4096 + n0 + arow) * 4096 + ahalf * 16;
  const float* ga = alph + ((size_t)bz * 4096 + n0 + arow) * 64;  // float2 stride
  __bf16* Pl = &Ps[arow * 32 + ahalf * 16];

  // B staging (Hc channels)
  const int sr = t >> 2;
  const int sc = t & 3;
  const __bf16* gB0 = Hc + ((size_t)bz * 512 + c0 + sr) * 4096 + sc * 8;
  const __bf16* gB1 = gB0 + (size_t)64 * 4096;
  __bf16* lB0 = &Bs[t * 8];
  __bf16* lB1 = &Bs[(t + 256) * 8];

  const int lane = t & 63;
  const int wv = t >> 6;
  const int wm = (wv & 1) * 64;
  const int wn = (wv >> 1) * 64;
  const int l15 = lane & 15;
  const int kg = lane >> 4;

  int aoff[4], boff[4];
#pragma unroll
  for (int i = 0; i < 4; ++i) aoff[i] = (wm + i * 16 + l15) * 32 + kg * 8;
#pragma unroll
  for (int j = 0; j < 4; ++j) boff[j] = (wn + j * 16 + l15) * 32 + kg * 8;

  floatx4 acc[4][4] = {};
  float alpha = 0.f;

  for (int kt = 0; kt < 128; ++kt) {
    const size_t ko = (size_t)kt * 32;
    async_cp16(gB0 + ko, lB0);
    async_cp16(gB1 + ko, lB1);
    if ((kt & 3) == 0) alpha = ga[(kt >> 2) * 2];
    const bf16x8 s0 = *(const bf16x8*)(Sp + ko);
    const bf16x8 s1 = *(const bf16x8*)(Sp + ko + 8);
    bf16x8 p0, p1;
#pragma unroll
    for (int j = 0; j < 8; ++j) {
      p0[j] = (__bf16)((float)s0[j] * alpha);
      p1[j] = (__bf16)((float)s1[j] * alpha);
    }
    *(bf16x8*)Pl = p0;
    *(bf16x8*)(Pl + 8) = p1;
    __syncthreads();
    bf16x8 af[4], bfr[4];
#pragma unroll
    for (int i = 0; i < 4; ++i) af[i] = *(const bf16x8*)&Ps[aoff[i]];
#pragma unroll
    for (int j = 0; j < 4; ++j) bfr[j] = *(const bf16x8*)&Bs[boff[j]];
#pragma unroll
    for (int i = 0; i < 4; ++i)
#pragma unroll
      for (int j = 0; j < 4; ++j)
        acc[i][j] = __builtin_amdgcn_mfma_f32_16x16x32_bf16(af[i], bfr[j],
                                                            acc[i][j], 0, 0, 0);
    __syncthreads();
  }

  __bf16* Ob = Z + (size_t)bz * 2097152;
  const int r0 = n0 + wm + (kg << 2);
#pragma unroll
  for (int i = 0; i < 4; ++i)
#pragma unroll
    for (int r = 0; r < 4; ++r) {
      const int row = r0 + i * 16 + r;
#pragma unroll
      for (int j = 0; j < 4; ++j) {
        const int col = c0 + wn + j * 16 + l15;
        Ob[(size_t)row * 512 + col] = (__bf16)acc[i][j][r];
      }
    }
}

// ---------------------------------------------------------------------------
// GroupNorm pass 1 + 2 (unchanged)
// ---------------------------------------------------------------------------
__global__ __launch_bounds__(256) void gn_stats(const float* __restrict__ x,
                                                float* __restrict__ part) {
  const int t = threadIdx.x;
  const size_t base = (size_t)blockIdx.x * 8192;
  const floatx4* xp = (const floatx4*)(x + base);
  float s = 0.f, ss = 0.f;
#pragma unroll
  for (int i = 0; i < 8; ++i) {
    floatx4 v = xp[t + i * 256];
#pragma unroll
    for (int k = 0; k < 4; ++k) {
      s += v[k];
      ss += v[k] * v[k];
    }
  }
#pragma unroll
  for (int off = 32; off; off >>= 1) {
    s += __shfl_down(s, off);
    ss += __shfl_down(ss, off);
  }
  __shared__ float red[8];
  if ((t & 63) == 0) {
    red[t >> 6] = s;
    red[4 + (t >> 6)] = ss;
  }
  __syncthreads();
  if (t == 0) {
    part[blockIdx.x * 2] = red[0] + red[1] + red[2] + red[3];
    part[blockIdx.x * 2 + 1] = red[4] + red[5] + red[6] + red[7];
  }
}

__global__ __launch_bounds__(256) void gn_finalize(
    const float* __restrict__ part, const float* __restrict__ gamma,
    const float* __restrict__ beta, float* __restrict__ sc,
    float* __restrict__ sh) {
  const int tid = blockIdx.x * 256 + threadIdx.x;
  const int b = tid >> 9, c = tid & 511;
  const int bg = b * 32 + (c >> 4);
  float s = 0.f, ss = 0.f;
#pragma unroll
  for (int k = 0; k < 8; ++k) {
    s += part[(bg * 8 + k) * 2];
    ss += part[(bg * 8 + k) * 2 + 1];
  }
  const float mean = s * (1.f / 65536.f);
  const float var = ss * (1.f / 65536.f) - mean * mean;
  const float rstd = rsqrtf(var + 1e-5f);
  const float g = gamma[c] * rstd;
  sc[tid] = g;
  sh[tid] = beta[c] - mean * g;
}

// ---------------------------------------------------------------------------
// GroupNorm pass 3: x[b][c][n] f32 -> Ht[b][n][c] bf16 AND Hc[b][c][n] bf16
// ---------------------------------------------------------------------------
__global__ __launch_bounds__(256) void gn_xform(const float* __restrict__ x,
                                                const float* __restrict__ sc,
                                                const float* __restrict__ sh,
                                                __bf16* __restrict__ Ht,
                                                __bf16* __restrict__ Hc) {
  __shared__ float tile[64][65];
  const int t = threadIdx.x;
  const int b = blockIdx.z;
  const int c0 = blockIdx.y * 64;
  const int n0 = blockIdx.x * 64;

#pragma unroll
  for (int i = 0; i < 4; ++i) {
    const int slot = i * 256 + t;
    const int c = slot >> 4;
    const int nc = (slot & 15) * 4;
    const int ch = c0 + c;
    const floatx4 v =
        *(const floatx4*)&x[((size_t)b * 512 + ch) * 4096 + n0 + nc];
    const float scl = sc[b * 512 + ch];
    const float shf = sh[b * 512 + ch];
    bf16x4 hv;
#pragma unroll
    for (int k = 0; k < 4; ++k) {
      const float f = v[k] * scl + shf;
      tile[c][nc + k] = f;
      hv[k] = (__bf16)f;
    }
    *(bf16x4*)&Hc[((size_t)b * 512 + ch) * 4096 + n0 + nc] = hv;
  }
  __syncthreads();
#pragma unroll
  for (int i = 0; i < 4; ++i) {
    const int slot = i * 256 + t;
    const int n = slot >> 4;
    const int cc = (slot & 15) * 4;
    bf16x4 o;
#pragma unroll
    for (int k = 0; k < 4; ++k) o[k] = (__bf16)tile[cc + k][n];
    *(bf16x4*)&Ht[((size_t)b * 4096 + n0 + n) * 512 + c0 + cc] = o;
  }
}

// ---------------------------------------------------------------------------
// transpose+convert 3 weights: o[a][b] = (bf16)w[b][a]. grid (8,8,3).
// ---------------------------------------------------------------------------
__global__ __launch_bounds__(256) void cvtT_kernel(const float* w0,
                                                   const float* w1,
                                                   const float* w2, __bf16* o0,
                                                   __bf16* o1, __bf16* o2) {
  __shared__ float tile[64][65];
  const int t = threadIdx.x;
  const int z = blockIdx.z;
  const float* w = z == 0 ? w0 : z == 1 ? w1 : w2;
  __bf16* o = z == 0 ? o0 : z == 1 ? o1 : o2;
  const int r0 = blockIdx.y * 64;  // input row
  const int d0 = blockIdx.x * 64;  // input col

#pragma unroll
  for (int i = 0; i < 4; ++i) {
    const int slot = i * 256 + t;
    const int r = slot >> 4;
    const int cc = (slot & 15) * 4;
    const floatx4 v = *(const floatx4*)&w[(size_t)(r0 + r) * 512 + d0 + cc];
#pragma unroll
    for (int k = 0; k < 4; ++k) tile[r][cc + k] = v[k];
  }
  __syncthreads();
#pragma unroll
  for (int i = 0; i < 4; ++i) {
    const int slot = i * 256 + t;
    const int d = slot >> 4;
    const int cc = (slot & 15) * 4;
    bf16x4 ov;
#pragma unroll
    for (int k = 0; k < 4; ++k) ov[k] = (__bf16)tile[cc + k][d];
    *(bf16x4*)&o[(size_t)(d0 + d) * 512 + r0 + cc] = ov;
  }
}

__global__ void cvt1_kernel(const float* __restrict__ w,
                            __bf16* __restrict__ o) {
  const int i = blockIdx.x * 256 + threadIdx.x;
  o[i] = (__bf16)w[i];
}

// u[j] = qscale * sum_d bq[d]*wk[d,j]; uq[512] = qscale * (bq.bk)
__global__ __launch_bounds__(256) void u_kernel(const float* __restrict__ wk,
                                                const float* __restrict__ bq,
                                                const float* __restrict__ bk,
                                                float* __restrict__ uq,
                                                float qscale) {
  const int j = blockIdx.x * 256 + threadIdx.x;
  float s = 0.f;
  for (int d = 0; d < 512; ++d) s += bq[d] * wk[d * 512 + j];
  uq[j] = qscale * s;
  if (j == 0) {
    float c = 0.f;
    for (int d = 0; d < 512; ++d) c += bq[d] * bk[d];
    uq[512] = qscale * c;
  }
}

// bias2[d] = sum_c wo[d,c]*bv[c] + bo[d]
__global__ __launch_bounds__(256) void bias2_kernel(const float* __restrict__ wo,
                                                    const float* __restrict__ bv,
                                                    const float* __restrict__ bo,
                                                    float* __restrict__ b2) {
  const int d = blockIdx.x * 256 + threadIdx.x;
  float s = 0.f;
  for (int c = 0; c < 512; ++c) s += wo[d * 512 + c] * bv[c];
  b2[d] = s + bo[d];
}

// wvec[row] = sum_j uq[j]*Ht[row,j] + uq[512].  grid 4096 x 256 (4 waves).
__global__ __launch_bounds__(256) void wvec_kernel(const __bf16* __restrict__ Ht,
                                                   const float* __restrict__ uq,
                                                   float* __restrict__ wvec) {
  const int t = threadIdx.x;
  const int row = blockIdx.x * 4 + (t >> 6);
  const int lane = t & 63;
  const bf16x8 h = *(const bf16x8*)(Ht + (size_t)row * 512 + lane * 8);
  const floatx4 u0 = *(const floatx4*)(uq + lane * 8);
  const floatx4 u1 = *(const floatx4*)(uq + lane * 8 + 4);
  float s = 0.f;
#pragma unroll
  for (int k = 0; k < 4; ++k) s += (float)h[k] * u0[k];
#pragma unroll
  for (int k = 0; k < 4; ++k) s += (float)h[4 + k] * u1[k];
#pragma unroll
  for (int off = 32; off; off >>= 1) s += __shfl_down(s, off);
  if (lane == 0) wvec[row] = s + uq[512];
}

// ---------------------------------------------------------------------------
extern "C" void kernel_launch(void* const* d_in, const int* in_sizes, int n_in,
                              void* d_out, int out_size, void* d_ws,
                              size_t ws_size, hipStream_t stream) {
  const float* x = (const float*)d_in[0];
  const float* gamma = (const float*)d_in[1];
  const float* beta = (const float*)d_in[2];
  const float* wq = (const float*)d_in[3];
  const float* bq = (const float*)d_in[4];
  const float* wk = (const float*)d_in[5];
  const float* bk = (const float*)d_in[6];
  const float* wv = (const float*)d_in[7];
  const float* bv = (const float*)d_in[8];
  const float* wo = (const float*)d_in[9];
  const float* bo = (const float*)d_in[10];

  // workspace layout (bf16 units)
  __bf16* ws = (__bf16*)d_ws;
  __bf16* wqT = ws;                  // 512*512 (transposed)
  __bf16* wkT = wqT + 262144;
  __bf16* wvT = wkT + 262144;
  __bf16* woB = wvT + 262144;        // straight
  __bf16* AqkT = woB + 262144;       // qscale * wk^T wq  -> [j][i]
  __bf16* Wb = AqkT + 262144;        // wo*wv -> [d][c']
  __bf16* Ht = Wb + 262144;          // [4][4096][512]
  __bf16* Hc = Ht + 8388608;         // [4][512][4096]
  __bf16* G = Hc + 8388608;          // [4][4096][512]
  __bf16* Z = G + 8388608;           // [4][4096][512]
  __bf16* SP = Z + 8388608;          // [4][4096][4096]  P'
  float2* gstats = (float2*)(SP + 67108864);  // [16384][32]
  float* uq = (float*)(gstats + 524288);      // [513]
  float* wvec = uq + 1024;                    // [16384]
  float* bias2 = wvec + 16384;                // [512]
  const size_t need = ((size_t)(6 * 262144 + 4 * 8388608 + 67108864)) * 2 +
                      4194304 + (1024 + 16384 + 512) * 4;
  if (ws_size < need) return;

  // gn scratch in SP region (overwritten later by gemm_qk)
  float* part = (float*)SP;  // [1024][2]
  float* scb = part + 2048;  // [4][512]
  float* shb = scb + 2048;   // [4][512]

  const float qscale = 0.04419417382415922f;  // 512^-0.5
  const long sH = 2097152;

  cvtT_kernel<<<dim3(8, 8, 3), 256, 0, stream>>>(wq, wk, wv, wqT, wkT, wvT);
  cvt1_kernel<<<1024, 256, 0, stream>>>(wo, woB);
  u_kernel<<<2, 256, 0, stream>>>(wk, bq, bk, uq, qscale);
  bias2_kernel<<<2, 256, 0, stream>>>(wo, bv, bo, bias2);

  // AqkT[j][i] = qscale * sum_d wkT[j,d]*wqT[i,d]
  gemm_bt<false><<<dim3(4, 4, 1), 256, 0, stream>>>(
      wkT, wqT, AqkT, nullptr, nullptr, 512, 512, 512, 0, 0, 0, 0, 512, 0,
      qscale);
  // Wb[d][c'] = sum_c woB[d,c]*wvT[c',c]
  gemm_bt<false><<<dim3(4, 4, 1), 256, 0, stream>>>(
      woB, wvT, Wb, nullptr, nullptr, 512, 512, 512, 0, 0, 0, 0, 512, 0, 1.0f);

  gn_stats<<<1024, 256, 0, stream>>>(x, part);
  gn_finalize<<<8, 256, 0, stream>>>(part, gamma, beta, scb, shb);
  gn_xform<<<dim3(64, 8, 4), 256, 0, stream>>>(x, scb, shb, Ht, Hc);

  wvec_kernel<<<4096, 256, 0, stream>>>(Ht, uq, wvec);

  // G[n][j] = sum_i Ht[n,i]*AqkT[j,i]
  gemm_bt<false><<<dim3(4, 32, 4), 256, 0, stream>>>(
      Ht, AqkT, G, nullptr, nullptr, 512, 512, 512, sH, 0, sH, 0, 512, 0, 1.0f);
  // P' + stats
  gemm_qk<<<dim3(32, 32, 4), 256, 0, stream>>>(G, Ht, wvec, SP, gstats);
  // alpha
  row_merge<<<64, 256, 0, stream>>>(gstats);
  // Z[n][c] = sum_m P[n,m]*Hc[c,m]
  gemm_pv<<<dim3(4, 32, 4), 256, 0, stream>>>(SP, Hc, (const float*)gstats, Z);
  // y[d][n] = x[d][n] + sum_c' Wb[d,c']*Z[n,c'] + bias2[d]
  gemm_bt<true><<<dim3(32, 4, 4), 256, 0, stream>>>(
      Wb, Z, d_out, bias2, x, 512, 512, 4096, 0, sH, sH, sH, 512, 1, 1.0f);
}

// Round 6
// 474.310 us; speedup vs baseline: 1.1773x; 1.1773x over previous
//
#include <hip/hip_runtime.h>

typedef __bf16 bf16x8 __attribute__((ext_vector_type(8)));
typedef __bf16 bf16x4 __attribute__((ext_vector_type(4)));
typedef float floatx4 __attribute__((ext_vector_type(4)));

#define AS1(p) ((const __attribute__((address_space(1))) unsigned int*)(p))
#define AS3(p) ((__attribute__((address_space(3))) unsigned int*)(p))

__device__ __forceinline__ void async_cp16(const void* g, void* l) {
  __builtin_amdgcn_global_load_lds(AS1(g), AS3(l), 16, 0, 0);
}

// ---------------------------------------------------------------------------
// Generic bf16 GEMM:  C[row][col] = scale * (sum_k A[row,k]*B[col,k] + bias)
// A: [M][K] k-contiguous (lda), B: [N][K] k-contiguous (ldb).
// swz=1: grid (128,1,B) remapped so 4 col-blocks of a row-strip share an XCD.
// colscale (OUT_F32 only): v *= colscale[bz*4096+col] before bias/residual.
// ---------------------------------------------------------------------------
template <bool OUT_F32>
__global__ __launch_bounds__(256, 2) void gemm_bt(
    const __bf16* __restrict__ A, const __bf16* __restrict__ B,
    void* __restrict__ Cv, const float* __restrict__ bias,
    const float* __restrict__ residual, const float* __restrict__ colscale,
    int lda, int ldb, int ldc, long sA, long sB, long sC, long sR, int K,
    int bias_mode, float scale, int swz) {
  __shared__ alignas(16) __bf16 As[128 * 32];
  __shared__ alignas(16) __bf16 Bs[128 * 32];

  const int t = threadIdx.x;
  const int bz = blockIdx.z;
  int bx = blockIdx.x, by = blockIdx.y;
  if (swz) {
    const int xcd = bx & 7, idx = bx >> 3;
    by = xcd + (idx >> 2) * 8;  // row strip 0..31
    bx = idx & 3;               // col block 0..3
  }
  const int m0 = by * 128;
  const int n0 = bx * 128;

  const __bf16* Ab = A + (size_t)bz * sA;
  const __bf16* Bb = B + (size_t)bz * sB;

  const int sr = t >> 2;
  const int sc = t & 3;
  const __bf16* gA0 = Ab + (size_t)(m0 + sr) * lda + sc * 8;
  const __bf16* gA1 = gA0 + (size_t)64 * lda;
  const __bf16* gB0 = Bb + (size_t)(n0 + sr) * ldb + sc * 8;
  const __bf16* gB1 = gB0 + (size_t)64 * ldb;
  __bf16* lA0 = &As[t * 8];
  __bf16* lA1 = &As[(t + 256) * 8];
  __bf16* lB0 = &Bs[t * 8];
  __bf16* lB1 = &Bs[(t + 256) * 8];

  const int lane = t & 63;
  const int wv = t >> 6;
  const int wm = (wv & 1) * 64;
  const int wn = (wv >> 1) * 64;
  const int l15 = lane & 15;
  const int kg = lane >> 4;

  int aoff[4], boff[4];
#pragma unroll
  for (int i = 0; i < 4; ++i) aoff[i] = (wm + i * 16 + l15) * 32 + kg * 8;
#pragma unroll
  for (int j = 0; j < 4; ++j) boff[j] = (wn + j * 16 + l15) * 32 + kg * 8;

  floatx4 acc[4][4] = {};

  const int KT = K >> 5;
  for (int kt = 0; kt < KT; ++kt) {
    const size_t ko = (size_t)kt * 32;
    async_cp16(gA0 + ko, lA0);
    async_cp16(gA1 + ko, lA1);
    async_cp16(gB0 + ko, lB0);
    async_cp16(gB1 + ko, lB1);
    __syncthreads();
    bf16x8 af[4], bfr[4];
#pragma unroll
    for (int i = 0; i < 4; ++i) af[i] = *(const bf16x8*)&As[aoff[i]];
#pragma unroll
    for (int j = 0; j < 4; ++j) bfr[j] = *(const bf16x8*)&Bs[boff[j]];
#pragma unroll
    for (int i = 0; i < 4; ++i)
#pragma unroll
      for (int j = 0; j < 4; ++j)
        acc[i][j] = __builtin_amdgcn_mfma_f32_16x16x32_bf16(af[i], bfr[j],
                                                            acc[i][j], 0, 0, 0);
    __syncthreads();
  }

  const int r0 = m0 + wm + (kg << 2);
  const int c0 = n0 + wn + l15;
#pragma unroll
  for (int i = 0; i < 4; ++i) {
#pragma unroll
    for (int r = 0; r < 4; ++r) {
      const int row = r0 + i * 16 + r;
      float brow = 0.f;
      if (bias_mode == 1) brow = bias[row];
#pragma unroll
      for (int j = 0; j < 4; ++j) {
        const int col = c0 + j * 16;
        float v = acc[i][j][r];
        if (OUT_F32 && colscale) v *= colscale[(size_t)bz * 4096 + col];
        if (bias_mode == 1) v += brow;
        v *= scale;
        const size_t off = (size_t)row * ldc + col;
        if (OUT_F32) {
          float* Cf = (float*)Cv + (size_t)bz * sC;
          if (residual) v += residual[(size_t)bz * sR + off];
          Cf[off] = v;
        } else {
          __bf16* Cb = (__bf16*)Cv + (size_t)bz * sC;
          Cb[off] = (__bf16)v;
        }
      }
    }
  }
}

// ---------------------------------------------------------------------------
// QK^T GEMM + P'' = exp(s - Mhat) with PRECOMPUTED safe row bound Mhat.
// s[n][m] = G[n,:]·Ht[m,:] + wvec[m];  Mhat[n] = sqrt(gn2[n])*sqrt(sred[0])
// + sred[1].  Writes P'' scattered (bf16) + per-(row,128-blk) sums Lb.
// grid (32 mblk, 32 nblk, 4).  Pure m97 K-loop; slim epilogue.
// ---------------------------------------------------------------------------
__global__ __launch_bounds__(256, 2) void gemm_qk(
    const __bf16* __restrict__ G, const __bf16* __restrict__ Ht,
    const float* __restrict__ wvec, const float* __restrict__ gn2,
    const float* __restrict__ sred, __bf16* __restrict__ SP,
    float* __restrict__ Lpart) {
  __shared__ alignas(16) __bf16 As[128 * 32];
  __shared__ alignas(16) __bf16 Bs[128 * 32];
  __shared__ float smq[128];
  __shared__ float smf[256];

  const int t = threadIdx.x;
  const int bz = blockIdx.z;
  const int m0 = blockIdx.x * 128;  // key cols
  const int n0 = blockIdx.y * 128;  // query rows
  const long sH = 2097152;

  const __bf16* Ab = G + (size_t)bz * sH;
  const __bf16* Bb = Ht + (size_t)bz * sH;

  const int sr = t >> 2;
  const int sc = t & 3;
  const __bf16* gA0 = Ab + (size_t)(n0 + sr) * 512 + sc * 8;
  const __bf16* gA1 = gA0 + (size_t)64 * 512;
  const __bf16* gB0 = Bb + (size_t)(m0 + sr) * 512 + sc * 8;
  const __bf16* gB1 = gB0 + (size_t)64 * 512;
  __bf16* lA0 = &As[t * 8];
  __bf16* lA1 = &As[(t + 256) * 8];
  __bf16* lB0 = &Bs[t * 8];
  __bf16* lB1 = &Bs[(t + 256) * 8];

  const int lane = t & 63;
  const int wv = t >> 6;
  const int wm = (wv & 1) * 64;  // query-row half
  const int wn = (wv >> 1) * 64; // key-col half
  const int l15 = lane & 15;
  const int kg = lane >> 4;

  int aoff[4], boff[4];
#pragma unroll
  for (int i = 0; i < 4; ++i) aoff[i] = (wm + i * 16 + l15) * 32 + kg * 8;
#pragma unroll
  for (int j = 0; j < 4; ++j) boff[j] = (wn + j * 16 + l15) * 32 + kg * 8;

  floatx4 acc[4][4] = {};

  for (int kt = 0; kt < 16; ++kt) {
    const size_t ko = (size_t)kt * 32;
    async_cp16(gA0 + ko, lA0);
    async_cp16(gA1 + ko, lA1);
    async_cp16(gB0 + ko, lB0);
    async_cp16(gB1 + ko, lB1);
    __syncthreads();
    bf16x8 af[4], bfr[4];
#pragma unroll
    for (int i = 0; i < 4; ++i) af[i] = *(const bf16x8*)&As[aoff[i]];
#pragma unroll
    for (int j = 0; j < 4; ++j) bfr[j] = *(const bf16x8*)&Bs[boff[j]];
#pragma unroll
    for (int i = 0; i < 4; ++i)
#pragma unroll
      for (int j = 0; j < 4; ++j)
        acc[i][j] = __builtin_amdgcn_mfma_f32_16x16x32_bf16(af[i], bfr[j],
                                                            acc[i][j], 0, 0, 0);
    __syncthreads();
  }

  // Mhat for this block's 128 query rows
  const float Hs = sqrtf(sred[0]);
  const float Ws = sred[1];
  if (t < 128) smq[t] = sqrtf(gn2[(size_t)bz * 4096 + n0 + t]) * Hs + Ws;
  __syncthreads();

  // col bias values for this thread's 4 col positions
  float wv4[4];
#pragma unroll
  for (int j = 0; j < 4; ++j)
    wv4[j] = wvec[(size_t)bz * 4096 + m0 + wn + j * 16 + l15];

  __bf16* Sb = SP + (size_t)bz * 16777216;
  const int wnh = wv >> 1;
#pragma unroll
  for (int i = 0; i < 4; ++i) {
#pragma unroll
    for (int r = 0; r < 4; ++r) {
      const int rl = wm + i * 16 + (kg << 2) + r;
      const float Mh = smq[rl];
      const size_t rowbase = (size_t)(n0 + rl) * 4096 + m0 + wn;
      float se = 0.f;
#pragma unroll
      for (int j = 0; j < 4; ++j) {
        const float p = __expf(acc[i][j][r] + wv4[j] - Mh);
        se += p;
        Sb[rowbase + j * 16 + l15] = (__bf16)p;
      }
#pragma unroll
      for (int off = 1; off < 16; off <<= 1) se += __shfl_xor(se, off);
      if (l15 == 0) smf[wnh * 128 + rl] = se;
    }
  }
  __syncthreads();
  if (t < 128)
    Lpart[((size_t)bz * 4096 + n0 + t) * 32 + blockIdx.x] =
        smf[t] + smf[128 + t];
}

// ---------------------------------------------------------------------------
// invL[n] = 1 / sum_32 Lpart[n][j]
// ---------------------------------------------------------------------------
__global__ __launch_bounds__(256) void lsum_kernel(const float* __restrict__ Lp,
                                                   float* __restrict__ invL) {
  const int row = blockIdx.x * 256 + threadIdx.x;
  const float* p = Lp + (size_t)row * 32;
  float L = 0.f;
#pragma unroll
  for (int j = 0; j < 32; ++j) L += p[j];
  invL[row] = 1.0f / L;
}

// ---------------------------------------------------------------------------
// gn2[row] = ||G[row,:]||^2   (one wave per row)
// ---------------------------------------------------------------------------
__global__ __launch_bounds__(256) void gnorm_kernel(const __bf16* __restrict__ G,
                                                    float* __restrict__ gn2) {
  const int t = threadIdx.x;
  const int row = blockIdx.x * 4 + (t >> 6);
  const int lane = t & 63;
  const bf16x8 g = *(const bf16x8*)(G + (size_t)row * 512 + lane * 8);
  float s = 0.f;
#pragma unroll
  for (int k = 0; k < 8; ++k) {
    const float f = (float)g[k];
    s += f * f;
  }
#pragma unroll
  for (int off = 32; off; off >>= 1) s += __shfl_down(s, off);
  if (lane == 0) gn2[row] = s;
}

// sred[0] = max hn2, sred[1] = max wvec   (single block)
__global__ __launch_bounds__(256) void reduce_kernel(
    const float* __restrict__ hn2, const float* __restrict__ wvec,
    float* __restrict__ sred) {
  const int t = threadIdx.x;
  float mh = 0.f, mw = -1e30f;
  for (int i = t; i < 16384; i += 256) {
    mh = fmaxf(mh, hn2[i]);
    mw = fmaxf(mw, wvec[i]);
  }
#pragma unroll
  for (int off = 32; off; off >>= 1) {
    mh = fmaxf(mh, __shfl_down(mh, off));
    mw = fmaxf(mw, __shfl_down(mw, off));
  }
  __shared__ float red[8];
  if ((t & 63) == 0) {
    red[t >> 6] = mh;
    red[4 + (t >> 6)] = mw;
  }
  __syncthreads();
  if (t == 0) {
    sred[0] = fmaxf(fmaxf(red[0], red[1]), fmaxf(red[2], red[3]));
    sred[1] = fmaxf(fmaxf(red[4], red[5]), fmaxf(red[6], red[7]));
  }
}

// ---------------------------------------------------------------------------
// GroupNorm passes (unchanged from R5)
// ---------------------------------------------------------------------------
__global__ __launch_bounds__(256) void gn_stats(const float* __restrict__ x,
                                                float* __restrict__ part) {
  const int t = threadIdx.x;
  const size_t base = (size_t)blockIdx.x * 8192;
  const floatx4* xp = (const floatx4*)(x + base);
  float s = 0.f, ss = 0.f;
#pragma unroll
  for (int i = 0; i < 8; ++i) {
    floatx4 v = xp[t + i * 256];
#pragma unroll
    for (int k = 0; k < 4; ++k) {
      s += v[k];
      ss += v[k] * v[k];
    }
  }
#pragma unroll
  for (int off = 32; off; off >>= 1) {
    s += __shfl_down(s, off);
    ss += __shfl_down(ss, off);
  }
  __shared__ float red[8];
  if ((t & 63) == 0) {
    red[t >> 6] = s;
    red[4 + (t >> 6)] = ss;
  }
  __syncthreads();
  if (t == 0) {
    part[blockIdx.x * 2] = red[0] + red[1] + red[2] + red[3];
    part[blockIdx.x * 2 + 1] = red[4] + red[5] + red[6] + red[7];
  }
}

__global__ __launch_bounds__(256) void gn_finalize(
    const float* __restrict__ part, const float* __restrict__ gamma,
    const float* __restrict__ beta, float* __restrict__ sc,
    float* __restrict__ sh) {
  const int tid = blockIdx.x * 256 + threadIdx.x;
  const int b = tid >> 9, c = tid & 511;
  const int bg = b * 32 + (c >> 4);
  float s = 0.f, ss = 0.f;
#pragma unroll
  for (int k = 0; k < 8; ++k) {
    s += part[(bg * 8 + k) * 2];
    ss += part[(bg * 8 + k) * 2 + 1];
  }
  const float mean = s * (1.f / 65536.f);
  const float var = ss * (1.f / 65536.f) - mean * mean;
  const float rstd = rsqrtf(var + 1e-5f);
  const float g = gamma[c] * rstd;
  sc[tid] = g;
  sh[tid] = beta[c] - mean * g;
}

__global__ __launch_bounds__(256) void gn_xform(const float* __restrict__ x,
                                                const float* __restrict__ sc,
                                                const float* __restrict__ sh,
                                                __bf16* __restrict__ Ht,
                                                __bf16* __restrict__ Hc) {
  __shared__ float tile[64][65];
  const int t = threadIdx.x;
  const int b = blockIdx.z;
  const int c0 = blockIdx.y * 64;
  const int n0 = blockIdx.x * 64;

#pragma unroll
  for (int i = 0; i < 4; ++i) {
    const int slot = i * 256 + t;
    const int c = slot >> 4;
    const int nc = (slot & 15) * 4;
    const int ch = c0 + c;
    const floatx4 v =
        *(const floatx4*)&x[((size_t)b * 512 + ch) * 4096 + n0 + nc];
    const float scl = sc[b * 512 + ch];
    const float shf = sh[b * 512 + ch];
    bf16x4 hv;
#pragma unroll
    for (int k = 0; k < 4; ++k) {
      const float f = v[k] * scl + shf;
      tile[c][nc + k] = f;
      hv[k] = (__bf16)f;
    }
    *(bf16x4*)&Hc[((size_t)b * 512 + ch) * 4096 + n0 + nc] = hv;
  }
  __syncthreads();
#pragma unroll
  for (int i = 0; i < 4; ++i) {
    const int slot = i * 256 + t;
    const int n = slot >> 4;
    const int cc = (slot & 15) * 4;
    bf16x4 o;
#pragma unroll
    for (int k = 0; k < 4; ++k) o[k] = (__bf16)tile[cc + k][n];
    *(bf16x4*)&Ht[((size_t)b * 4096 + n0 + n) * 512 + c0 + cc] = o;
  }
}

// ---------------------------------------------------------------------------
// weight prep (unchanged from R5)
// ---------------------------------------------------------------------------
__global__ __launch_bounds__(256) void cvtT_kernel(const float* w0,
                                                   const float* w1,
                                                   const float* w2, __bf16* o0,
                                                   __bf16* o1, __bf16* o2) {
  __shared__ float tile[64][65];
  const int t = threadIdx.x;
  const int z = blockIdx.z;
  const float* w = z == 0 ? w0 : z == 1 ? w1 : w2;
  __bf16* o = z == 0 ? o0 : z == 1 ? o1 : o2;
  const int r0 = blockIdx.y * 64;
  const int d0 = blockIdx.x * 64;

#pragma unroll
  for (int i = 0; i < 4; ++i) {
    const int slot = i * 256 + t;
    const int r = slot >> 4;
    const int cc = (slot & 15) * 4;
    const floatx4 v = *(const floatx4*)&w[(size_t)(r0 + r) * 512 + d0 + cc];
#pragma unroll
    for (int k = 0; k < 4; ++k) tile[r][cc + k] = v[k];
  }
  __syncthreads();
#pragma unroll
  for (int i = 0; i < 4; ++i) {
    const int slot = i * 256 + t;
    const int d = slot >> 4;
    const int cc = (slot & 15) * 4;
    bf16x4 ov;
#pragma unroll
    for (int k = 0; k < 4; ++k) ov[k] = (__bf16)tile[cc + k][d];
    *(bf16x4*)&o[(size_t)(d0 + d) * 512 + r0 + cc] = ov;
  }
}

__global__ void cvt1_kernel(const float* __restrict__ w,
                            __bf16* __restrict__ o) {
  const int i = blockIdx.x * 256 + threadIdx.x;
  o[i] = (__bf16)w[i];
}

__global__ __launch_bounds__(256) void u_kernel(const float* __restrict__ wk,
                                                const float* __restrict__ bq,
                                                const float* __restrict__ bk,
                                                float* __restrict__ uq,
                                                float qscale) {
  const int j = blockIdx.x * 256 + threadIdx.x;
  float s = 0.f;
  for (int d = 0; d < 512; ++d) s += bq[d] * wk[d * 512 + j];
  uq[j] = qscale * s;
  if (j == 0) {
    float c = 0.f;
    for (int d = 0; d < 512; ++d) c += bq[d] * bk[d];
    uq[512] = qscale * c;
  }
}

__global__ __launch_bounds__(256) void bias2_kernel(const float* __restrict__ wo,
                                                    const float* __restrict__ bv,
                                                    const float* __restrict__ bo,
                                                    float* __restrict__ b2) {
  const int d = blockIdx.x * 256 + threadIdx.x;
  float s = 0.f;
  for (int c = 0; c < 512; ++c) s += wo[d * 512 + c] * bv[c];
  b2[d] = s + bo[d];
}

// wvec[row] = u·h_row + uq[512]; hn2[row] = ||h_row||^2
__global__ __launch_bounds__(256) void wvec_kernel(const __bf16* __restrict__ Ht,
                                                   const float* __restrict__ uq,
                                                   float* __restrict__ wvec,
                                                   float* __restrict__ hn2) {
  const int t = threadIdx.x;
  const int row = blockIdx.x * 4 + (t >> 6);
  const int lane = t & 63;
  const bf16x8 h = *(const bf16x8*)(Ht + (size_t)row * 512 + lane * 8);
  const floatx4 u0 = *(const floatx4*)(uq + lane * 8);
  const floatx4 u1 = *(const floatx4*)(uq + lane * 8 + 4);
  float s = 0.f, n2 = 0.f;
#pragma unroll
  for (int k = 0; k < 4; ++k) {
    const float f0 = (float)h[k], f1 = (float)h[4 + k];
    s += f0 * u0[k] + f1 * u1[k];
    n2 += f0 * f0 + f1 * f1;
  }
#pragma unroll
  for (int off = 32; off; off >>= 1) {
    s += __shfl_down(s, off);
    n2 += __shfl_down(n2, off);
  }
  if (lane == 0) {
    wvec[row] = s + uq[512];
    hn2[row] = n2;
  }
}

// ---------------------------------------------------------------------------
extern "C" void kernel_launch(void* const* d_in, const int* in_sizes, int n_in,
                              void* d_out, int out_size, void* d_ws,
                              size_t ws_size, hipStream_t stream) {
  const float* x = (const float*)d_in[0];
  const float* gamma = (const float*)d_in[1];
  const float* beta = (const float*)d_in[2];
  const float* wq = (const float*)d_in[3];
  const float* bq = (const float*)d_in[4];
  const float* wk = (const float*)d_in[5];
  const float* bk = (const float*)d_in[6];
  const float* wv = (const float*)d_in[7];
  const float* bv = (const float*)d_in[8];
  const float* wo = (const float*)d_in[9];
  const float* bo = (const float*)d_in[10];

  __bf16* ws = (__bf16*)d_ws;
  __bf16* wqT = ws;                  // 512*512
  __bf16* wkT = wqT + 262144;
  __bf16* wvT = wkT + 262144;
  __bf16* woB = wvT + 262144;
  __bf16* AqkT = woB + 262144;
  __bf16* Wb = AqkT + 262144;
  __bf16* Ht = Wb + 262144;          // [4][4096][512]
  __bf16* Hc = Ht + 8388608;         // [4][512][4096]
  __bf16* G = Hc + 8388608;          // [4][4096][512]
  __bf16* Z = G + 8388608;           // [4][4096][512]
  __bf16* SP = Z + 8388608;          // [4][4096][4096]  P''
  float* Lpart = (float*)(SP + 67108864);  // [16384][32]
  float* invL = Lpart + 524288;            // [16384]
  float* gn2 = invL + 16384;               // [16384]
  float* hn2 = gn2 + 16384;                // [16384]
  float* wvec = hn2 + 16384;               // [16384]
  float* uq = wvec + 16384;                // [513]
  float* bias2 = uq + 1024;                // [512]
  float* sred = bias2 + 512;               // [2]
  const size_t need = ((size_t)(6 * 262144 + 4 * 8388608 + 67108864)) * 2 +
                      (524288 + 4 * 16384 + 1024 + 512 + 64) * 4;
  if (ws_size < need) return;

  // gn scratch in SP region (overwritten later by gemm_qk)
  float* part = (float*)SP;  // [1024][2]
  float* scb = part + 2048;
  float* shb = scb + 2048;

  const float qscale = 0.04419417382415922f;  // 512^-0.5
  const long sH = 2097152;

  cvtT_kernel<<<dim3(8, 8, 3), 256, 0, stream>>>(wq, wk, wv, wqT, wkT, wvT);
  cvt1_kernel<<<1024, 256, 0, stream>>>(wo, woB);
  u_kernel<<<2, 256, 0, stream>>>(wk, bq, bk, uq, qscale);
  bias2_kernel<<<2, 256, 0, stream>>>(wo, bv, bo, bias2);

  // AqkT[j][i] = qscale * wk^T wq;  Wb[d][c'] = wo*wv
  gemm_bt<false><<<dim3(4, 4, 1), 256, 0, stream>>>(
      wkT, wqT, AqkT, nullptr, nullptr, nullptr, 512, 512, 512, 0, 0, 0, 0,
      512, 0, qscale, 0);
  gemm_bt<false><<<dim3(4, 4, 1), 256, 0, stream>>>(
      woB, wvT, Wb, nullptr, nullptr, nullptr, 512, 512, 512, 0, 0, 0, 0, 512,
      0, 1.0f, 0);

  gn_stats<<<1024, 256, 0, stream>>>(x, part);
  gn_finalize<<<8, 256, 0, stream>>>(part, gamma, beta, scb, shb);
  gn_xform<<<dim3(64, 8, 4), 256, 0, stream>>>(x, scb, shb, Ht, Hc);

  wvec_kernel<<<4096, 256, 0, stream>>>(Ht, uq, wvec, hn2);

  // G[n][j] = Ht[n,:]·AqkT[j,:]
  gemm_bt<false><<<dim3(4, 32, 4), 256, 0, stream>>>(
      Ht, AqkT, G, nullptr, nullptr, nullptr, 512, 512, 512, sH, 0, sH, 0, 512,
      0, 1.0f, 0);

  gnorm_kernel<<<4096, 256, 0, stream>>>(G, gn2);
  reduce_kernel<<<1, 256, 0, stream>>>(hn2, wvec, sred);

  // P'' = exp(s - Mhat) + row-block sums
  gemm_qk<<<dim3(32, 32, 4), 256, 0, stream>>>(G, Ht, wvec, gn2, sred, SP,
                                               Lpart);
  lsum_kernel<<<64, 256, 0, stream>>>(Lpart, invL);

  // Z'[n][c] = sum_m P''[n,m]*Hc[c,m]   (pure m97, XCD-swizzled)
  gemm_bt<false><<<dim3(128, 1, 4), 256, 0, stream>>>(
      SP, Hc, Z, nullptr, nullptr, nullptr, 4096, 4096, 512, 16777216, sH, sH,
      0, 4096, 0, 1.0f, 1);

  // y[d][n] = x[d][n] + invL[n]*(Wb·Z')[d][n] + bias2[d]
  gemm_bt<true><<<dim3(32, 4, 4), 256, 0, stream>>>(
      Wb, Z, d_out, bias2, x, invL, 512, 512, 4096, 0, sH, sH, sH, 512, 1,
      1.0f, 0);
}

// Round 7
// 403.480 us; speedup vs baseline: 1.3840x; 1.1755x over previous
//
#include <hip/hip_runtime.h>

typedef __bf16 bf16x8 __attribute__((ext_vector_type(8)));
typedef __bf16 bf16x4 __attribute__((ext_vector_type(4)));
typedef float floatx4 __attribute__((ext_vector_type(4)));

#define AS1(p) ((const __attribute__((address_space(1))) unsigned int*)(p))
#define AS3(p) ((__attribute__((address_space(3))) unsigned int*)(p))

__device__ __forceinline__ void async_cp16(const void* g, void* l) {
  __builtin_amdgcn_global_load_lds(AS1(g), AS3(l), 16, 0, 0);
}

// ---------------------------------------------------------------------------
// Generic bf16 GEMM:  C[row][col] = scale * (sum_k A[row,k]*B[col,k] + bias)
// A: [M][K] k-contiguous (lda), B: [N][K] k-contiguous (ldb).
// swz=1: grid (128,1,B) remapped so 4 col-blocks of a row-strip share an XCD.
// colscale (OUT_F32 only): v *= colscale[bz*4096+col] before bias/residual.
// ---------------------------------------------------------------------------
template <bool OUT_F32>
__global__ __launch_bounds__(256, 2) void gemm_bt(
    const __bf16* __restrict__ A, const __bf16* __restrict__ B,
    void* __restrict__ Cv, const float* __restrict__ bias,
    const float* __restrict__ residual, const float* __restrict__ colscale,
    int lda, int ldb, int ldc, long sA, long sB, long sC, long sR, int K,
    int bias_mode, float scale, int swz) {
  __shared__ alignas(16) __bf16 As[128 * 32];
  __shared__ alignas(16) __bf16 Bs[128 * 32];

  const int t = threadIdx.x;
  const int bz = blockIdx.z;
  int bx = blockIdx.x, by = blockIdx.y;
  if (swz) {
    const int xcd = bx & 7, idx = bx >> 3;
    by = xcd + (idx >> 2) * 8;  // row strip 0..31
    bx = idx & 3;               // col block 0..3
  }
  const int m0 = by * 128;
  const int n0 = bx * 128;

  const __bf16* Ab = A + (size_t)bz * sA;
  const __bf16* Bb = B + (size_t)bz * sB;

  const int sr = t >> 2;
  const int sc = t & 3;
  const __bf16* gA0 = Ab + (size_t)(m0 + sr) * lda + sc * 8;
  const __bf16* gA1 = gA0 + (size_t)64 * lda;
  const __bf16* gB0 = Bb + (size_t)(n0 + sr) * ldb + sc * 8;
  const __bf16* gB1 = gB0 + (size_t)64 * ldb;
  __bf16* lA0 = &As[t * 8];
  __bf16* lA1 = &As[(t + 256) * 8];
  __bf16* lB0 = &Bs[t * 8];
  __bf16* lB1 = &Bs[(t + 256) * 8];

  const int lane = t & 63;
  const int wv = t >> 6;
  const int wm = (wv & 1) * 64;
  const int wn = (wv >> 1) * 64;
  const int l15 = lane & 15;
  const int kg = lane >> 4;

  int aoff[4], boff[4];
#pragma unroll
  for (int i = 0; i < 4; ++i) aoff[i] = (wm + i * 16 + l15) * 32 + kg * 8;
#pragma unroll
  for (int j = 0; j < 4; ++j) boff[j] = (wn + j * 16 + l15) * 32 + kg * 8;

  floatx4 acc[4][4] = {};

  const int KT = K >> 5;
  for (int kt = 0; kt < KT; ++kt) {
    const size_t ko = (size_t)kt * 32;
    async_cp16(gA0 + ko, lA0);
    async_cp16(gA1 + ko, lA1);
    async_cp16(gB0 + ko, lB0);
    async_cp16(gB1 + ko, lB1);
    __syncthreads();
    bf16x8 af[4], bfr[4];
#pragma unroll
    for (int i = 0; i < 4; ++i) af[i] = *(const bf16x8*)&As[aoff[i]];
#pragma unroll
    for (int j = 0; j < 4; ++j) bfr[j] = *(const bf16x8*)&Bs[boff[j]];
#pragma unroll
    for (int i = 0; i < 4; ++i)
#pragma unroll
      for (int j = 0; j < 4; ++j)
        acc[i][j] = __builtin_amdgcn_mfma_f32_16x16x32_bf16(af[i], bfr[j],
                                                            acc[i][j], 0, 0, 0);
    __syncthreads();
  }

  const int r0 = m0 + wm + (kg << 2);
  const int c0 = n0 + wn + l15;
#pragma unroll
  for (int i = 0; i < 4; ++i) {
#pragma unroll
    for (int r = 0; r < 4; ++r) {
      const int row = r0 + i * 16 + r;
      float brow = 0.f;
      if (bias_mode == 1) brow = bias[row];
#pragma unroll
      for (int j = 0; j < 4; ++j) {
        const int col = c0 + j * 16;
        float v = acc[i][j][r];
        if (OUT_F32 && colscale) v *= colscale[(size_t)bz * 4096 + col];
        if (bias_mode == 1) v += brow;
        v *= scale;
        const size_t off = (size_t)row * ldc + col;
        if (OUT_F32) {
          float* Cf = (float*)Cv + (size_t)bz * sC;
          if (residual) v += residual[(size_t)bz * sR + off];
          Cf[off] = v;
        } else {
          __bf16* Cb = (__bf16*)Cv + (size_t)bz * sC;
          Cb[off] = (__bf16)v;
        }
      }
    }
  }
}

// ---------------------------------------------------------------------------
// Two small 512x512x512 GEMMs in one launch. grid (4,4,2).
// z=0: AqkT = qscale * wkT·wqT^T ; z=1: Wb = woB·wvT^T
// ---------------------------------------------------------------------------
__global__ __launch_bounds__(256, 2) void gemm_small(
    const __bf16* __restrict__ A0, const __bf16* __restrict__ B0,
    __bf16* __restrict__ C0, const __bf16* __restrict__ A1,
    const __bf16* __restrict__ B1, __bf16* __restrict__ C1, float scale0) {
  __shared__ alignas(16) __bf16 As[128 * 32];
  __shared__ alignas(16) __bf16 Bs[128 * 32];

  const int t = threadIdx.x;
  const int z = blockIdx.z;
  const __bf16* A = z ? A1 : A0;
  const __bf16* B = z ? B1 : B0;
  __bf16* C = z ? C1 : C0;
  const float scale = z ? 1.0f : scale0;
  const int m0 = blockIdx.y * 128;
  const int n0 = blockIdx.x * 128;

  const int sr = t >> 2;
  const int sc = t & 3;
  const __bf16* gA0 = A + (size_t)(m0 + sr) * 512 + sc * 8;
  const __bf16* gA1 = gA0 + (size_t)64 * 512;
  const __bf16* gB0 = B + (size_t)(n0 + sr) * 512 + sc * 8;
  const __bf16* gB1 = gB0 + (size_t)64 * 512;
  __bf16* lA0 = &As[t * 8];
  __bf16* lA1 = &As[(t + 256) * 8];
  __bf16* lB0 = &Bs[t * 8];
  __bf16* lB1 = &Bs[(t + 256) * 8];

  const int lane = t & 63;
  const int wvv = t >> 6;
  const int wm = (wvv & 1) * 64;
  const int wn = (wvv >> 1) * 64;
  const int l15 = lane & 15;
  const int kg = lane >> 4;

  int aoff[4], boff[4];
#pragma unroll
  for (int i = 0; i < 4; ++i) aoff[i] = (wm + i * 16 + l15) * 32 + kg * 8;
#pragma unroll
  for (int j = 0; j < 4; ++j) boff[j] = (wn + j * 16 + l15) * 32 + kg * 8;

  floatx4 acc[4][4] = {};

  for (int kt = 0; kt < 16; ++kt) {
    const size_t ko = (size_t)kt * 32;
    async_cp16(gA0 + ko, lA0);
    async_cp16(gA1 + ko, lA1);
    async_cp16(gB0 + ko, lB0);
    async_cp16(gB1 + ko, lB1);
    __syncthreads();
    bf16x8 af[4], bfr[4];
#pragma unroll
    for (int i = 0; i < 4; ++i) af[i] = *(const bf16x8*)&As[aoff[i]];
#pragma unroll
    for (int j = 0; j < 4; ++j) bfr[j] = *(const bf16x8*)&Bs[boff[j]];
#pragma unroll
    for (int i = 0; i < 4; ++i)
#pragma unroll
      for (int j = 0; j < 4; ++j)
        acc[i][j] = __builtin_amdgcn_mfma_f32_16x16x32_bf16(af[i], bfr[j],
                                                            acc[i][j], 0, 0, 0);
    __syncthreads();
  }

  const int r0 = m0 + wm + (kg << 2);
  const int c0 = n0 + wn + l15;
#pragma unroll
  for (int i = 0; i < 4; ++i)
#pragma unroll
    for (int r = 0; r < 4; ++r) {
      const int row = r0 + i * 16 + r;
#pragma unroll
      for (int j = 0; j < 4; ++j)
        C[(size_t)row * 512 + c0 + j * 16] = (__bf16)(acc[i][j][r] * scale);
    }
}

// ---------------------------------------------------------------------------
// QK^T GEMM + P'' = exp(s - Mhat); Mhat from IN-KERNEL ||g_row|| (accumulated
// from A-fragments, bitwise identical across m-blocks) * sqrt(max||h||^2)
// + max wvec.  Writes P'' scattered bf16 + per-(row,128-blk) sums Lpart.
// grid (32 mblk, 32 nblk, 4).
// ---------------------------------------------------------------------------
__global__ __launch_bounds__(256, 2) void gemm_qk(
    const __bf16* __restrict__ G, const __bf16* __restrict__ Ht,
    const float* __restrict__ wvec, const float* __restrict__ sred,
    __bf16* __restrict__ SP, float* __restrict__ Lpart) {
  __shared__ alignas(16) __bf16 As[128 * 32];
  __shared__ alignas(16) __bf16 Bs[128 * 32];
  __shared__ float smq[128];
  __shared__ float smf[256];

  const int t = threadIdx.x;
  const int bz = blockIdx.z;
  const int m0 = blockIdx.x * 128;  // key cols
  const int n0 = blockIdx.y * 128;  // query rows
  const long sH = 2097152;

  const __bf16* Ab = G + (size_t)bz * sH;
  const __bf16* Bb = Ht + (size_t)bz * sH;

  const int sr = t >> 2;
  const int sc = t & 3;
  const __bf16* gA0 = Ab + (size_t)(n0 + sr) * 512 + sc * 8;
  const __bf16* gA1 = gA0 + (size_t)64 * 512;
  const __bf16* gB0 = Bb + (size_t)(m0 + sr) * 512 + sc * 8;
  const __bf16* gB1 = gB0 + (size_t)64 * 512;
  __bf16* lA0 = &As[t * 8];
  __bf16* lA1 = &As[(t + 256) * 8];
  __bf16* lB0 = &Bs[t * 8];
  __bf16* lB1 = &Bs[(t + 256) * 8];

  const int lane = t & 63;
  const int wv = t >> 6;
  const int wm = (wv & 1) * 64;  // query-row half
  const int wn = (wv >> 1) * 64; // key-col half
  const int l15 = lane & 15;
  const int kg = lane >> 4;

  int aoff[4], boff[4];
#pragma unroll
  for (int i = 0; i < 4; ++i) aoff[i] = (wm + i * 16 + l15) * 32 + kg * 8;
#pragma unroll
  for (int j = 0; j < 4; ++j) boff[j] = (wn + j * 16 + l15) * 32 + kg * 8;

  floatx4 acc[4][4] = {};
  float gsq[4] = {};

  for (int kt = 0; kt < 16; ++kt) {
    const size_t ko = (size_t)kt * 32;
    async_cp16(gA0 + ko, lA0);
    async_cp16(gA1 + ko, lA1);
    async_cp16(gB0 + ko, lB0);
    async_cp16(gB1 + ko, lB1);
    __syncthreads();
    bf16x8 af[4], bfr[4];
#pragma unroll
    for (int i = 0; i < 4; ++i) af[i] = *(const bf16x8*)&As[aoff[i]];
#pragma unroll
    for (int j = 0; j < 4; ++j) bfr[j] = *(const bf16x8*)&Bs[boff[j]];
#pragma unroll
    for (int i = 0; i < 4; ++i)
#pragma unroll
      for (int j = 0; j < 4; ++j)
        acc[i][j] = __builtin_amdgcn_mfma_f32_16x16x32_bf16(af[i], bfr[j],
                                                            acc[i][j], 0, 0, 0);
#pragma unroll
    for (int i = 0; i < 4; ++i)
#pragma unroll
      for (int e = 0; e < 8; ++e) {
        const float f = (float)af[i][e];
        gsq[i] += f * f;
      }
    __syncthreads();
  }

  // Mhat per row from in-register ||g||^2 (rows wm + i*16 + l15)
  const float Hs = sqrtf(sred[0]);
  const float Ws = sred[1];
#pragma unroll
  for (int i = 0; i < 4; ++i) {
    float g2 = gsq[i];
    g2 += __shfl_xor(g2, 16);
    g2 += __shfl_xor(g2, 32);
    if (kg == 0) smq[wm + i * 16 + l15] = sqrtf(g2) * Hs + Ws;
  }
  __syncthreads();

  float wv4[4];
#pragma unroll
  for (int j = 0; j < 4; ++j)
    wv4[j] = wvec[(size_t)bz * 4096 + m0 + wn + j * 16 + l15];

  __bf16* Sb = SP + (size_t)bz * 16777216;
  const int wnh = wv >> 1;
#pragma unroll
  for (int i = 0; i < 4; ++i) {
#pragma unroll
    for (int r = 0; r < 4; ++r) {
      const int rl = wm + i * 16 + (kg << 2) + r;
      const float Mh = smq[rl];
      const size_t rowbase = (size_t)(n0 + rl) * 4096 + m0 + wn;
      float se = 0.f;
#pragma unroll
      for (int j = 0; j < 4; ++j) {
        const float p = __expf(acc[i][j][r] + wv4[j] - Mh);
        se += p;
        Sb[rowbase + j * 16 + l15] = (__bf16)p;
      }
#pragma unroll
      for (int off = 1; off < 16; off <<= 1) se += __shfl_xor(se, off);
      if (l15 == 0) smf[wnh * 128 + rl] = se;
    }
  }
  __syncthreads();
  if (t < 128)
    Lpart[((size_t)bz * 4096 + n0 + t) * 32 + blockIdx.x] =
        smf[t] + smf[128 + t];
}

// ---------------------------------------------------------------------------
// invL[n] = 1 / sum_32 Lpart[n][j]
// ---------------------------------------------------------------------------
__global__ __launch_bounds__(256) void lsum_kernel(const float* __restrict__ Lp,
                                                   float* __restrict__ invL) {
  const int row = blockIdx.x * 256 + threadIdx.x;
  const float* p = Lp + (size_t)row * 32;
  float L = 0.f;
#pragma unroll
  for (int j = 0; j < 32; ++j) L += p[j];
  invL[row] = 1.0f / L;
}

// sred[0] = max hn2, sred[1] = max wvec   (single block, float4)
__global__ __launch_bounds__(256) void reduce_kernel(
    const float* __restrict__ hn2, const float* __restrict__ wvec,
    float* __restrict__ sred) {
  const int t = threadIdx.x;
  const floatx4* h4 = (const floatx4*)hn2;
  const floatx4* w4 = (const floatx4*)wvec;
  float mh = 0.f, mw = -1e30f;
  for (int i = t; i < 4096; i += 256) {
    const floatx4 a = h4[i], b = w4[i];
#pragma unroll
    for (int k = 0; k < 4; ++k) {
      mh = fmaxf(mh, a[k]);
      mw = fmaxf(mw, b[k]);
    }
  }
#pragma unroll
  for (int off = 32; off; off >>= 1) {
    mh = fmaxf(mh, __shfl_down(mh, off));
    mw = fmaxf(mw, __shfl_down(mw, off));
  }
  __shared__ float red[8];
  if ((t & 63) == 0) {
    red[t >> 6] = mh;
    red[4 + (t >> 6)] = mw;
  }
  __syncthreads();
  if (t == 0) {
    sred[0] = fmaxf(fmaxf(red[0], red[1]), fmaxf(red[2], red[3]));
    sred[1] = fmaxf(fmaxf(red[4], red[5]), fmaxf(red[6], red[7]));
  }
}

// ---------------------------------------------------------------------------
// GroupNorm pass 1: partial sums. grid 1024.
// ---------------------------------------------------------------------------
__global__ __launch_bounds__(256) void gn_stats(const float* __restrict__ x,
                                                float* __restrict__ part) {
  const int t = threadIdx.x;
  const size_t base = (size_t)blockIdx.x * 8192;
  const floatx4* xp = (const floatx4*)(x + base);
  float s = 0.f, ss = 0.f;
#pragma unroll
  for (int i = 0; i < 8; ++i) {
    floatx4 v = xp[t + i * 256];
#pragma unroll
    for (int k = 0; k < 4; ++k) {
      s += v[k];
      ss += v[k] * v[k];
    }
  }
#pragma unroll
  for (int off = 32; off; off >>= 1) {
    s += __shfl_down(s, off);
    ss += __shfl_down(ss, off);
  }
  __shared__ float red[8];
  if ((t & 63) == 0) {
    red[t >> 6] = s;
    red[4 + (t >> 6)] = ss;
  }
  __syncthreads();
  if (t == 0) {
    part[blockIdx.x * 2] = red[0] + red[1] + red[2] + red[3];
    part[blockIdx.x * 2 + 1] = red[4] + red[5] + red[6] + red[7];
  }
}

// ---------------------------------------------------------------------------
// GroupNorm pass 2 (finalize fused): x[b][c][n] -> Ht[b][n][c], Hc[b][c][n]
// ---------------------------------------------------------------------------
__global__ __launch_bounds__(256) void gn_xform(const float* __restrict__ x,
                                                const float* __restrict__ part,
                                                const float* __restrict__ gamma,
                                                const float* __restrict__ beta,
                                                __bf16* __restrict__ Ht,
                                                __bf16* __restrict__ Hc) {
  __shared__ float tile[64][65];
  __shared__ float lsc[64], lsh[64];
  const int t = threadIdx.x;
  const int b = blockIdx.z;
  const int c0 = blockIdx.y * 64;
  const int n0 = blockIdx.x * 64;

  if (t < 64) {
    const int ch = c0 + t;
    const int bg = b * 32 + (ch >> 4);
    float s = 0.f, ss = 0.f;
#pragma unroll
    for (int k = 0; k < 8; ++k) {
      s += part[(bg * 8 + k) * 2];
      ss += part[(bg * 8 + k) * 2 + 1];
    }
    const float mean = s * (1.f / 65536.f);
    const float var = ss * (1.f / 65536.f) - mean * mean;
    const float rstd = rsqrtf(var + 1e-5f);
    const float g = gamma[ch] * rstd;
    lsc[t] = g;
    lsh[t] = beta[ch] - mean * g;
  }
  __syncthreads();

#pragma unroll
  for (int i = 0; i < 4; ++i) {
    const int slot = i * 256 + t;
    const int c = slot >> 4;
    const int nc = (slot & 15) * 4;
    const int ch = c0 + c;
    const floatx4 v =
        *(const floatx4*)&x[((size_t)b * 512 + ch) * 4096 + n0 + nc];
    const float scl = lsc[c];
    const float shf = lsh[c];
    bf16x4 hv;
#pragma unroll
    for (int k = 0; k < 4; ++k) {
      const float f = v[k] * scl + shf;
      tile[c][nc + k] = f;
      hv[k] = (__bf16)f;
    }
    *(bf16x4*)&Hc[((size_t)b * 512 + ch) * 4096 + n0 + nc] = hv;
  }
  __syncthreads();
#pragma unroll
  for (int i = 0; i < 4; ++i) {
    const int slot = i * 256 + t;
    const int n = slot >> 4;
    const int cc = (slot & 15) * 4;
    bf16x4 o;
#pragma unroll
    for (int k = 0; k < 4; ++k) o[k] = (__bf16)tile[cc + k][n];
    *(bf16x4*)&Ht[((size_t)b * 4096 + n0 + n) * 512 + c0 + cc] = o;
  }
}

// ---------------------------------------------------------------------------
// weight prep: z<3 -> transpose+cvt wq/wk/wv; z==3 -> straight cvt wo.
// grid (8,8,4).
// ---------------------------------------------------------------------------
__global__ __launch_bounds__(256) void cvt_kernel(const float* w0,
                                                  const float* w1,
                                                  const float* w2,
                                                  const float* w3, __bf16* o0,
                                                  __bf16* o1, __bf16* o2,
                                                  __bf16* o3) {
  __shared__ float tile[64][65];
  const int t = threadIdx.x;
  const int z = blockIdx.z;
  const int r0 = blockIdx.y * 64;
  const int d0 = blockIdx.x * 64;

  if (z == 3) {
#pragma unroll
    for (int i = 0; i < 4; ++i) {
      const int slot = i * 256 + t;
      const int r = slot >> 4;
      const int cc = (slot & 15) * 4;
      const floatx4 v = *(const floatx4*)&w3[(size_t)(r0 + r) * 512 + d0 + cc];
      bf16x4 ov;
#pragma unroll
      for (int k = 0; k < 4; ++k) ov[k] = (__bf16)v[k];
      *(bf16x4*)&o3[(size_t)(r0 + r) * 512 + d0 + cc] = ov;
    }
    return;
  }
  const float* w = z == 0 ? w0 : z == 1 ? w1 : w2;
  __bf16* o = z == 0 ? o0 : z == 1 ? o1 : o2;
#pragma unroll
  for (int i = 0; i < 4; ++i) {
    const int slot = i * 256 + t;
    const int r = slot >> 4;
    const int cc = (slot & 15) * 4;
    const floatx4 v = *(const floatx4*)&w[(size_t)(r0 + r) * 512 + d0 + cc];
#pragma unroll
    for (int k = 0; k < 4; ++k) tile[r][cc + k] = v[k];
  }
  __syncthreads();
#pragma unroll
  for (int i = 0; i < 4; ++i) {
    const int slot = i * 256 + t;
    const int d = slot >> 4;
    const int cc = (slot & 15) * 4;
    bf16x4 ov;
#pragma unroll
    for (int k = 0; k < 4; ++k) ov[k] = (__bf16)tile[cc + k][d];
    *(bf16x4*)&o[(size_t)(d0 + d) * 512 + r0 + cc] = ov;
  }
}

// ---------------------------------------------------------------------------
// fused bias prep, one block per output element. grid 1025.
// b<512:   uq[b]    = qscale * sum_d bq[d]*wk[d*512+b]
// b<1024:  bias2[b-512] = sum_c wo[(b-512)*512+c]*bv[c] + bo[b-512]
// b==1024: uq[512]  = qscale * sum_d bq[d]*bk[d]
// ---------------------------------------------------------------------------
__global__ __launch_bounds__(256) void prep_kernel(
    const float* __restrict__ wk, const float* __restrict__ bq,
    const float* __restrict__ bk, const float* __restrict__ wo,
    const float* __restrict__ bv, const float* __restrict__ bo,
    float* __restrict__ uq, float* __restrict__ bias2, float qscale) {
  const int bidx = blockIdx.x;
  const int t = threadIdx.x;
  float s = 0.f;
  if (bidx < 512) {
    s = bq[t] * wk[(size_t)t * 512 + bidx] +
        bq[t + 256] * wk[(size_t)(t + 256) * 512 + bidx];
  } else if (bidx < 1024) {
    const int d = bidx - 512;
    s = wo[(size_t)d * 512 + t] * bv[t] +
        wo[(size_t)d * 512 + t + 256] * bv[t + 256];
  } else {
    s = bq[t] * bk[t] + bq[t + 256] * bk[t + 256];
  }
#pragma unroll
  for (int off = 32; off; off >>= 1) s += __shfl_down(s, off);
  __shared__ float red[4];
  if ((t & 63) == 0) red[t >> 6] = s;
  __syncthreads();
  if (t == 0) {
    const float tot = red[0] + red[1] + red[2] + red[3];
    if (bidx < 512)
      uq[bidx] = qscale * tot;
    else if (bidx < 1024)
      bias2[bidx - 512] = tot + bo[bidx - 512];
    else
      uq[512] = qscale * tot;
  }
}

// wvec[row] = u·h_row + uq[512]; hn2[row] = ||h_row||^2
__global__ __launch_bounds__(256) void wvec_kernel(const __bf16* __restrict__ Ht,
                                                   const float* __restrict__ uq,
                                                   float* __restrict__ wvec,
                                                   float* __restrict__ hn2) {
  const int t = threadIdx.x;
  const int row = blockIdx.x * 4 + (t >> 6);
  const int lane = t & 63;
  const bf16x8 h = *(const bf16x8*)(Ht + (size_t)row * 512 + lane * 8);
  const floatx4 u0 = *(const floatx4*)(uq + lane * 8);
  const floatx4 u1 = *(const floatx4*)(uq + lane * 8 + 4);
  float s = 0.f, n2 = 0.f;
#pragma unroll
  for (int k = 0; k < 4; ++k) {
    const float f0 = (float)h[k], f1 = (float)h[4 + k];
    s += f0 * u0[k] + f1 * u1[k];
    n2 += f0 * f0 + f1 * f1;
  }
#pragma unroll
  for (int off = 32; off; off >>= 1) {
    s += __shfl_down(s, off);
    n2 += __shfl_down(n2, off);
  }
  if (lane == 0) {
    wvec[row] = s + uq[512];
    hn2[row] = n2;
  }
}

// ---------------------------------------------------------------------------
extern "C" void kernel_launch(void* const* d_in, const int* in_sizes, int n_in,
                              void* d_out, int out_size, void* d_ws,
                              size_t ws_size, hipStream_t stream) {
  const float* x = (const float*)d_in[0];
  const float* gamma = (const float*)d_in[1];
  const float* beta = (const float*)d_in[2];
  const float* wq = (const float*)d_in[3];
  const float* bq = (const float*)d_in[4];
  const float* wk = (const float*)d_in[5];
  const float* bk = (const float*)d_in[6];
  const float* wv = (const float*)d_in[7];
  const float* bv = (const float*)d_in[8];
  const float* wo = (const float*)d_in[9];
  const float* bo = (const float*)d_in[10];

  __bf16* ws = (__bf16*)d_ws;
  __bf16* wqT = ws;                  // 512*512
  __bf16* wkT = wqT + 262144;
  __bf16* wvT = wkT + 262144;
  __bf16* woB = wvT + 262144;
  __bf16* AqkT = woB + 262144;
  __bf16* Wb = AqkT + 262144;
  __bf16* Ht = Wb + 262144;          // [4][4096][512]
  __bf16* Hc = Ht + 8388608;         // [4][512][4096]
  __bf16* G = Hc + 8388608;          // [4][4096][512]
  __bf16* Z = G + 8388608;           // [4][4096][512]
  __bf16* SP = Z + 8388608;          // [4][4096][4096]  P''
  float* Lpart = (float*)(SP + 67108864);  // [16384][32]
  float* invL = Lpart + 524288;            // [16384]
  float* hn2 = invL + 16384;               // [16384]
  float* wvec = hn2 + 16384;               // [16384]
  float* uq = wvec + 16384;                // [513]
  float* bias2 = uq + 1024;                // [512]
  float* sred = bias2 + 512;               // [2]
  const size_t need = ((size_t)(6 * 262144 + 4 * 8388608 + 67108864)) * 2 +
                      (524288 + 3 * 16384 + 1024 + 512 + 64) * 4;
  if (ws_size < need) return;

  // gn scratch in SP region (overwritten later by gemm_qk)
  float* part = (float*)SP;  // [1024][2]

  const float qscale = 0.04419417382415922f;  // 512^-0.5
  const long sH = 2097152;

  cvt_kernel<<<dim3(8, 8, 4), 256, 0, stream>>>(wq, wk, wv, wo, wqT, wkT, wvT,
                                                woB);
  prep_kernel<<<1025, 256, 0, stream>>>(wk, bq, bk, wo, bv, bo, uq, bias2,
                                        qscale);
  // AqkT = qscale*wk^T wq ; Wb = wo*wv   (one launch)
  gemm_small<<<dim3(4, 4, 2), 256, 0, stream>>>(wkT, wqT, AqkT, woB, wvT, Wb,
                                                qscale);

  gn_stats<<<1024, 256, 0, stream>>>(x, part);
  gn_xform<<<dim3(64, 8, 4), 256, 0, stream>>>(x, part, gamma, beta, Ht, Hc);

  wvec_kernel<<<4096, 256, 0, stream>>>(Ht, uq, wvec, hn2);

  // G[n][j] = Ht[n,:]·AqkT[j,:]
  gemm_bt<false><<<dim3(4, 32, 4), 256, 0, stream>>>(
      Ht, AqkT, G, nullptr, nullptr, nullptr, 512, 512, 512, sH, 0, sH, 0, 512,
      0, 1.0f, 0);

  reduce_kernel<<<1, 256, 0, stream>>>(hn2, wvec, sred);

  // P'' = exp(s - Mhat) + row-block sums (||g|| computed in-kernel)
  gemm_qk<<<dim3(32, 32, 4), 256, 0, stream>>>(G, Ht, wvec, sred, SP, Lpart);
  lsum_kernel<<<64, 256, 0, stream>>>(Lpart, invL);

  // Z'[n][c] = sum_m P''[n,m]*Hc[c,m]   (pure m97, XCD-swizzled)
  gemm_bt<false><<<dim3(128, 1, 4), 256, 0, stream>>>(
      SP, Hc, Z, nullptr, nullptr, nullptr, 4096, 4096, 512, 16777216, sH, sH,
      0, 4096, 0, 1.0f, 1);

  // y[d][n] = x[d][n] + invL[n]*(Wb·Z')[d][n] + bias2[d]
  gemm_bt<true><<<dim3(32, 4, 4), 256, 0, stream>>>(
      Wb, Z, d_out, bias2, x, invL, 512, 512, 4096, 0, sH, sH, sH, 512, 1,
      1.0f, 0);
}